// Round 8
// baseline (347.909 us; speedup 1.0000x reference)
//
#include <hip/hip_runtime.h>
#include <cstdint>

#define NPIX  1024
#define NH    992
#define NEDGE 1984
#define NSORT 2048
#define NGRP  31
#define HFS   4300
#define POOLN (NPIX + 2*HFS)   // 9624 u32 entries

typedef unsigned long long u64;
typedef unsigned int u32;

// ---- root_ encoding ----
// 0 == dead/unlabeled.
// type = bits[62,64): 0 = pool-backed, 1 = inline x1, 2 = inline x2.
// pool-backed: sL[0,11) | off[11,25) | len[25,36) | cap[36,47)
// inline: entry k at bits[26k, 26k+26), entry = lab<<16 | cnt
static __device__ __forceinline__ u64 packRoot(int sL,int off,int len,int cap){
    return (u64)(u32)(sL & 0x7FF) | ((u64)(u32)(off & 0x3FFF) << 11) |
           ((u64)(u32)(len & 0x7FF) << 25) | ((u64)(u32)(cap & 0x7FF) << 36);
}
#define R_SL(R)  ((int)((R) & 0x7FF))
#define R_OFF(R) ((int)(((R)>>11) & 0x3FFF))
#define R_LEN(R) ((int)(((R)>>25) & 0x7FF))
#define R_CAP(R) ((int)(((R)>>36) & 0x7FF))
#define EMASK 0x3FFFFFFu

static __device__ __forceinline__ int rdl(int v, int l){ return __builtin_amdgcn_readlane(v, l); }

static __device__ __forceinline__ u64 sxor64(u64 v, int m){
    u32 lo = (u32)__shfl_xor((int)(v & 0xFFFFFFFFull), m, 64);
    u32 hi = (u32)__shfl_xor((int)(v >> 32), m, 64);
    return ((u64)hi << 32) | lo;
}

// edge id -> endpoints (reference order: 992 horizontal then 992 vertical)
static __device__ __forceinline__ void edgeAB(int e, int &a, int &b){
    if (e < NH) { int r = (int)((unsigned)e / 31u); a = e + r; b = a + 1; }
    else        { a = e - NH; b = a + 32; }
}

static __device__ __forceinline__ int winBase(int wslot){
    int bb = wslot >> 6;
    int win = wslot & 63;
    int wy = win >> 3, wx = win & 7;
    return bb * 65536 + (wy * 32) * 256 + wx * 32;
}

// in-register compare-exchange: x at lower global index
#define CE(x, y, up) { u64 _a=(x), _b=(y); bool _lt=(_a<_b); \
    u64 _mn=_lt?_a:_b, _mx=_lt?_b:_a; (x)=(up)?_mn:_mx; (y)=(up)?_mx:_mn; }
// cross-lane compare-exchange via shfl_xor
#define CEX(x, xm, keepmin) { u64 _p=sxor64((x),(xm)); bool _lt=((x)<_p); \
    u64 _mn=_lt?(x):_p, _mx=_lt?_p:(x); (x)=(keepmin)?_mn:_mx; }

static __device__ __forceinline__ int wredi(int v){
    #pragma unroll
    for (int o = 32; o > 0; o >>= 1) v += __shfl_xor(v, o, 64);
    return v;
}
static __device__ __forceinline__ float wredf(float v){
    #pragma unroll
    for (int o = 32; o > 0; o >>= 1) v += __shfl_xor(v, o, 64);
    return v;
}

// ===== fully fused: one block per (window, phase); 256 blocks x 64 threads =====
__global__ __launch_bounds__(64) void malis_kernel(
    const float* __restrict__ pred,
    const float* __restrict__ target,
    const float* __restrict__ lr_p,
    const float* __restrict__ lrp_p,
    float* __restrict__ out)
{
    const int lane = threadIdx.x;
    const int bid  = blockIdx.x;          // 0..255
    const int ph   = bid & 1;
    const int wslot= bid >> 1;
    const int base = winBase(wslot);
    const u64 ltm = (1ull << lane) - 1;

    // ---- LDS (~91 KB; 1 block/CU) ----
    __shared__ __align__(16) u32 Ks_[NSORT];   // 8192 sorted edge ids (this phase)
    __shared__ u64   root_[NPIX];              // 8192
    __shared__ u32   pool_[POOLN];             // 38496
    __shared__ unsigned short Q_[NPIX];        // 2048
    __shared__ float Qw_[NPIX];                // 4096
    __shared__ u32   claim_[NPIX];             // 4096  mixed winner+loser claims
    __shared__ u32   blockClaim_[NPIX];        // 4096  blockers (kill-x or non-elig on x)
    __shared__ short par_[NPIX];               // 2048  parent[9:0] | labeled<<15
    __shared__ short H_[NPIX + 1];             // 2050
    __shared__ float predL[NPIX];              // 4096
    __shared__ float costs[NEDGE];             // 7936
    __shared__ short seg[NPIX];                // 2048
    __shared__ unsigned char tgtL[NPIX];       // 1024
    __shared__ unsigned char gtcL[NEDGE];      // 1984
    __shared__ u32   rowmaskL[32];             // 128
    __shared__ u32   fgL[32];                  // 128
    __shared__ unsigned short baseL[33];       // 66

    // early scratch overlaid on pool_ (dead until drain merges write it)
    u32* runPar = (u32*)pool_;                                  // 512 u32
    unsigned short* labIdRun = (unsigned short*)(runPar + 512); // 512 u16

    // ---- load window; (target==0) row bitmasks via ballot ----
    for (int j = 0; j < 16; ++j) {
        int i = lane + 64 * j;
        int r = (j << 1) + (lane >> 5), c = lane & 31;
        float pv = pred[base + r * 256 + c];
        float tv = target[base + r * 256 + c];
        predL[i] = pv;
        tgtL[i]  = (unsigned char)tv;
        u64 zb = __ballot(tv == 0.0f);
        if (lane == 0) {
            rowmaskL[2*j]     = (u32)zb;
            rowmaskL[2*j + 1] = (u32)(zb >> 32);
        }
    }
    for (int x = lane; x < 512; x += 64) runPar[x] = (u32)x;
    __builtin_amdgcn_wave_barrier();

    // ---- dilate 5x in lanes 0..31 (lane r holds row-r mask) ----
    if (lane < 32) {
        u32 m = rowmaskL[lane];
        #pragma unroll
        for (int it = 0; it < 5; ++it) {
            u32 um = __shfl(m, (lane == 0) ? 0 : lane - 1, 64);
            if (lane == 0) um = 0;
            u32 dm = __shfl(m, (lane == 31) ? 31 : lane + 1, 64);
            if (lane == 31) dm = 0;
            m = m | (m << 1) | (m >> 1) | um | dm;
        }
        u32 f = ~m;
        fgL[lane] = f;
        int ns = __popc(f & ~(f << 1));
        int x = ns;
        #pragma unroll
        for (int off = 1; off < 32; off <<= 1) {
            int y = __shfl(x, (lane >= off) ? lane - off : 0, 64);
            if (lane >= off) x += y;
        }
        baseL[lane] = (unsigned short)(x - ns);
        if (lane == 31) baseL[32] = (unsigned short)x;
    }
    __builtin_amdgcn_wave_barrier();
    const int nRuns = (int)baseL[32];

    // ---- CCL (8-conn) as union-find over row runs; single wave ----
    for (;;) {
        bool chg = false;
        for (int j = 0; j < 16; ++j) {
            int i = lane + 64 * j;
            int r = i >> 5, c = i & 31;
            if (r == 0) continue;
            u32 fr = fgL[r];
            if (!((fr >> c) & 1u)) continue;
            u32 fu = fgL[r - 1];
            u32 nb = fu & (u32)((7ull << c) >> 1);
            if (!nb) continue;
            u32 Sr = fr & ~(fr << 1);
            int a = (int)baseL[r] + __popc(Sr & ((2u << c) - 1u)) - 1;
            for (;;) { int p = (int)runPar[a]; if (p == a) break; a = p; }
            u32 Su = fu & ~(fu << 1);
            int bu = (int)baseL[r - 1];
            while (nb) {
                int cc = __ffs((int)nb) - 1; nb &= nb - 1;
                int b = bu + __popc(Su & ((2u << cc) - 1u)) - 1;
                for (;;) { int p = (int)runPar[b]; if (p == b) break; b = p; }
                if (a != b) {
                    int mnr = a < b ? a : b;
                    int mxr = a ^ b ^ mnr;
                    atomicMin(&runPar[mxr], (u32)mnr);
                    chg = true;
                    a = mnr;
                }
            }
        }
        if (!__ballot(chg)) break;
        for (int x = lane; x < nRuns; x += 64) {
            u32 p = runPar[x];
            runPar[x] = runPar[p];
        }
        __builtin_amdgcn_wave_barrier();
    }

    // compact label ids over run roots via ballot prefix (deterministic)
    {
        int kacc = 0;
        for (int x0 = 0; x0 < nRuns; x0 += 64) {
            int x = x0 + lane;
            bool isr = (x < nRuns) && ((int)runPar[x] == x);
            u64 bm = __ballot(isr);
            if (isr) labIdRun[x] = (unsigned short)(kacc + (int)__popcll(bm & ltm));
            kacc += (int)__popcll(bm);
        }
    }
    __builtin_amdgcn_wave_barrier();

    // seg per pixel
    for (int j = 0; j < 16; ++j) {
        int i = lane + 64 * j;
        int r = i >> 5, c = i & 31;
        u32 fr = fgL[r];
        short s = 0;
        if ((fr >> c) & 1u) {
            u32 Sr = fr & ~(fr << 1);
            int x = (int)baseL[r] + __popc(Sr & ((2u << c) - 1u)) - 1;
            for (;;) { int p = (int)runPar[x]; if (p == x) break; x = p; }
            s = (short)((int)labIdRun[x] + 1);
        }
        seg[i] = s;
    }

    // ---- edge costs ----
    for (int e = lane; e < NEDGE; e += 64) {
        int a, b2; edgeAB(e, a, b2);
        costs[e] = predL[a] + predL[b2];
        gtcL[e]  = (unsigned char)(tgtL[a] + tgtL[b2]);
    }
    __builtin_amdgcn_wave_barrier();

    // ---- register-resident bitonic sort of 2048 u64 keys (this phase) ----
    u64 sk[32];
    #pragma unroll
    for (int r = 0; r < 32; ++r) {
        int e = lane * 32 + r;
        u64 kv = ~0ULL;
        if (e < NEDGE) {
            float cv = costs[e];
            int g = gtcL[e];
            if (ph == 0) { if (g > 20) cv = 20.0f; }
            else         { if (g < 10) cv = 0.0f; }
            kv = (((u64)(~__float_as_uint(cv))) << 32) | (u32)e;
        }
        sk[r] = kv;
    }
    #pragma unroll
    for (int kk2 = 2; kk2 <= 32; kk2 <<= 1) {
        #pragma unroll
        for (int j = kk2 >> 1; j > 0; j >>= 1) {
            #pragma unroll
            for (int r = 0; r < 32; ++r) {
                if ((r & j) == 0) {
                    bool up = (kk2 == 32) ? ((lane & 1) == 0) : ((r & kk2) == 0);
                    CE(sk[r], sk[r | j], up);
                }
            }
        }
    }
    #pragma unroll
    for (int kk2 = 64; kk2 <= 2048; kk2 <<= 1) {
        const bool up = ((lane & (kk2 >> 5)) == 0);
        #pragma unroll
        for (int j = kk2 >> 1; j >= 32; j >>= 1) {
            const int xm = j >> 5;
            const bool keepmin = (((lane & xm) == 0) == up);
            #pragma unroll
            for (int r = 0; r < 32; ++r) { CEX(sk[r], xm, keepmin); }
        }
        #pragma unroll
        for (int j = 16; j > 0; j >>= 1) {
            #pragma unroll
            for (int r = 0; r < 32; ++r) {
                if ((r & j) == 0) { CE(sk[r], sk[r | j], up); }
            }
        }
    }
    #pragma unroll
    for (int r = 0; r < 32; r += 4) {
        uint4 v4;
        v4.x = (u32)sk[r]; v4.y = (u32)sk[r+1]; v4.z = (u32)sk[r+2]; v4.w = (u32)sk[r+3];
        *(uint4*)&Ks_[lane * 32 + r] = v4;
    }

    // ---- union-find init; labeled pixel i starts as INLINE singleton ----
    for (int i = lane; i < NPIX; i += 64) {
        short s2 = seg[i];
        par_[i] = (short)(i | (s2 ? 0x8000 : 0));
        root_[i] = s2 ? ((1ull << 62) | ((u32)(unsigned short)s2 << 16) | 1u) : 0ull;
        H_[i] = 0;
        claim_[i] = ~0u;
        blockClaim_[i] = ~0u;
    }
    if (lane == 0) H_[NPIX] = 0;
    __builtin_amdgcn_wave_barrier();

    // ---- pool allocator + gc (rare path) ----
    u32 bump = NPIX;
    u32 halfEnd = NPIX + HFS;
    int curHalf = 0;

    auto do_gc = [&]() {
        u32 tgt = (curHalf == 0) ? (u32)(NPIX + HFS) : (u32)NPIX;
        u32 nb = tgt;
        for (int c = 0; c < 16; ++c) {
            int i0 = c * 64 + lane;
            u64 Ri = root_[i0];
            bool live = (Ri != 0) && ((Ri >> 62) == 0);
            u64 rbm = __ballot(live);
            while (rbm) {
                int j = __ffsll(rbm) - 1; rbm &= rbm - 1;
                int r = c * 64 + j;
                u64 R = root_[r];
                int len = R_LEN(R);
                int off = R_OFF(R);
                for (int t = lane; t < len; t += 64) {
                    u32 v2 = pool_[off + t];
                    pool_[nb + t] = v2;
                }
                __builtin_amdgcn_wave_barrier();
                if (lane == 0) root_[r] = packRoot(R_SL(R), (int)nb, len, len);
                nb += (u32)len;
            }
        }
        bump = nb;
        halfEnd = tgt + HFS;
        curHalf ^= 1;
    };

    // ---- Kruskal drain with fused accounting + same-label cluster scan ----
    // Protocol per round:
    //   claim_ : min-tag over {all alive lanes' losers} U {weighted lanes' winners}
    //   blockClaim_ : min-tag over {weighted lanes' losers} U {NON-eligible weighted winners}
    //   eligible (W inline1, L inline1, same label):
    //       go = won claim_[loser] && lane < blockMin(winner)
    //       -> whole same-winner cluster proceeds in ONE round; weights via
    //          lane-order prefix (neg weight == 0 closed-form, pos = prefix*cnt)
    //   non-eligible weighted: go = won claim_[loser] && won claim_[winner]  (old rule)
    //   plumbing/mixed: go = won claim_[loser]
    // Invariants: a lane winning claim_[W] is the global-min claimant of W =>
    // no eligible lane precedes it; blockers block all eligibles after them =>
    // exact Kruskal (lane) order of set updates is preserved.
    int qn = 0;
    u32 rnd = 1;
    int curE = (int)Ks_[lane];
    for (int g2 = 0; g2 < NGRP; ++g2) {
        int nextE = (g2 + 1 < NGRP) ? (int)Ks_[(g2 + 1) * 64 + lane] : 0;
        const int myE = curE;
        int ea, eb2; edgeAB(myE, ea, eb2);
        int ra = ea, rb = eb2;
        int laA, laB;
        for (;;) {
            int va = (int)(unsigned short)par_[ra];
            int vb = (int)(unsigned short)par_[rb];
            int pa = va & 0x3FF, pb = vb & 0x3FF;
            bool fa = (pa != ra), fb = (pb != rb);
            if (!fa && !fb) { laA = va >> 15; laB = vb >> 15; break; }
            int ga = (int)(unsigned short)par_[pa];
            int gb = (int)(unsigned short)par_[pb];
            if (fa) { par_[ra] = (short)ga; ra = ga & 0x3FF; }
            if (fb) { par_[rb] = (short)gb; rb = gb & 0x3FF; }
        }
        bool alive = (ra != rb);

        for (;;) {
            if (!__ballot(alive)) break;
            const bool av = alive;
            const u32 tagBase = (0x03FFFFFFu - rnd) << 6;
            const u32 tag = tagBase | (u32)lane;
            ++rnd;
            int mn = ra < rb ? ra : rb;
            int mx = ra ^ rb ^ mn;
            int winner = (laA == laB) ? mn : (laA ? ra : rb);
            int loser  = (laA == laB) ? mx : (laA ? rb : ra);
            bool wgt = (laA & laB) != 0;

            // pre-claim root reads (valid for any proceeding lane: exclusivity)
            u64 RW = 0, RL = 0;
            if (av && wgt) { RW = root_[mn]; RL = root_[mx]; }
            u32 ew0 = (u32)RW & EMASK, el0 = (u32)RL & EMASK;
            bool elig = av && wgt && ((RW >> 62) == 1ull) && ((RL >> 62) == 1ull)
                        && ((ew0 >> 16) == (el0 >> 16));

            if (av)          atomicMin(&claim_[loser],  tag);
            if (av && wgt) { atomicMin(&claim_[winner], tag);
                             atomicMin(&blockClaim_[loser], tag); }
            if (av && wgt && !elig) atomicMin(&blockClaim_[winner], tag);

            bool go = false;
            if (av) {
                u32 lc = claim_[loser];
                bool selL = (lc == tag);
                if (!wgt) go = selL;
                else {
                    u32 wc = claim_[winner];
                    u32 bw = blockClaim_[winner];
                    int blockMin = ((bw & ~63u) == tagBase) ? (int)(bw & 63u) : 64;
                    go = selL && (elig ? (lane < blockMin) : (wc == tag));
                }
            }
            u64 wm = __ballot(go && wgt);
            int qidx = qn + (int)__popcll(wm & ltm);
            qn += (int)__popcll(wm);
            if (go) par_[loser] = (short)winner;

            // ---- same-label cluster scan (eligible go lanes), one round per chain ----
            u64 scanB = __ballot(go && elig);
            int cWv = (int)(ew0 & 0xFFFF);
            int cbv = (int)(el0 & 0xFFFF);
            if (scanB) {
                u64 pend = scanB;
                while (pend) {
                    int l0 = __ffsll(pend) - 1;
                    int w0 = rdl(mn, l0);
                    bool inC = (((scanB >> lane) & 1ull) != 0) && (mn == w0);
                    u64 mk = __ballot(inC);
                    pend &= ~mk;
                    int cW0 = rdl(cWv, l0);
                    int pre = 0, tot = 0;
                    u64 t = mk;
                    while (t) {
                        int li = __ffsll(t) - 1; t &= t - 1;
                        int cbi = rdl(cbv, li);
                        if (li < lane) pre += cbi;
                        tot += cbi;
                    }
                    if (inC) {
                        int sLaEff = cW0 + pre;
                        Qw_[qidx] = ph ? (float)(sLaEff * cbv) : 0.0f;  // neg: sa*sb-same==0
                        Q_[qidx]  = (unsigned short)myE;
                        root_[mx] = 0;
                        if (lane == 63 - __clzll(mk))
                            root_[mn] = (1ull << 62) |
                                (u64)((ew0 & 0x3FF0000u) | (u32)(cW0 + tot));
                    }
                }
            }

            // ---- per-lane inline merge (non-eligible go weighted) ----
            bool needPool = false;
            if (go && wgt && !elig) {
                int tW = (int)(RW >> 62), tL2 = (int)(RL >> 62);
                if (tW != 0 && tL2 != 0) {
                    u32 a0 = (u32)RW & EMASK, a1 = (u32)(RW >> 26) & EMASK;
                    u32 b0 = (u32)RL & EMASK, b1 = (u32)(RL >> 26) & EMASK;
                    u32 la0 = a0 >> 16, la1 = a1 >> 16;
                    u32 lb0 = b0 >> 16, lb1 = b1 >> 16;
                    int ca0 = (int)(a0 & 0xFFFF), ca1 = (int)(a1 & 0xFFFF);
                    int cb0 = (int)(b0 & 0xFFFF), cb1 = (int)(b1 & 0xFFFF);
                    int sLa = ca0 + ((tW == 2) ? ca1 : 0);
                    int sLb = cb0 + ((tL2 == 2) ? cb1 : 0);
                    int same = 0;
                    if (lb0 == la0) same += ca0 * cb0;
                    else if (tW == 2 && lb0 == la1) same += ca1 * cb0;
                    if (tL2 == 2) {
                        if (lb1 == la0) same += ca0 * cb1;
                        else if (tW == 2 && lb1 == la1) same += ca1 * cb1;
                    }
                    u32 r0 = a0, r1 = (tW == 2) ? a1 : 0;
                    int n = tW; bool ovf = false;
                    if (lb0 == la0) r0 += (u32)cb0;
                    else if (tW == 2 && lb0 == la1) r1 += (u32)cb0;
                    else { if (n == 1) { r1 = b0; n = 2; } else ovf = true; }
                    if (tL2 == 2) {
                        if (lb1 == la0) r0 += (u32)cb1;
                        else if (tW == 2 && lb1 == la1) r1 += (u32)cb1;
                        else { if (n == 1) { r1 = b1; n = 2; } else ovf = true; }
                    }
                    if (!ovf) {
                        root_[mn] = ((u64)(u32)n << 62) | ((u64)r1 << 26) | r0;
                        root_[mx] = 0;
                        Qw_[qidx] = (float)(ph ? same : (sLa * sLb - same));
                        Q_[qidx]  = (unsigned short)myE;
                    } else needPool = true;
                } else needPool = true;
            }

            // ---- wave-wide pool merges (rare) ----
            u64 pm = __ballot(needPool);
            while (pm) {
                int f = __ffsll(pm) - 1; pm &= pm - 1;
                int A  = rdl(mn, f),  B  = rdl(mx, f);
                int e  = rdl(myE, f), qi = rdl(qidx, f);
                u64 RA = root_[A], RB = root_[B];
                int tA = (int)(RA >> 62), tB = (int)(RB >> 62);
                int lenA = tA ? tA : R_LEN(RA);
                int lenB = tB ? tB : R_LEN(RB);
                if (bump + (u32)(lenA + lenB + 8) > halfEnd) {
                    do_gc();
                    RA = root_[A]; RB = root_[B];
                    tA = (int)(RA >> 62); tB = (int)(RB >> 62);
                    lenA = tA ? tA : R_LEN(RA);
                    lenB = tB ? tB : R_LEN(RB);
                }
                int sLa, sLb;
                int offA = 0, capA = 0, offB = 0, capB = 0;
                if (tA == 0) { sLa = R_SL(RA); offA = R_OFF(RA); capA = R_CAP(RA); }
                else {
                    u32 a0 = (u32)RA & EMASK, a1 = (u32)(RA >> 26) & EMASK;
                    sLa = (int)(a0 & 0xFFFF) + ((tA == 2) ? (int)(a1 & 0xFFFF) : 0);
                }
                if (tB == 0) { sLb = R_SL(RB); offB = R_OFF(RB); capB = R_CAP(RB); }
                else {
                    u32 b0 = (u32)RB & EMASK, b1 = (u32)(RB >> 26) & EMASK;
                    sLb = (int)(b0 & 0xFFFF) + ((tB == 2) ? (int)(b1 & 0xFFFF) : 0);
                }
                u32 eA = 0, eB = 0;
                if (lenA <= 64) {
                    if (tA == 0) { if (lane < lenA) eA = pool_[offA + lane]; }
                    else {
                        u32 a0 = (u32)RA & EMASK, a1 = (u32)(RA >> 26) & EMASK;
                        eA = (lane == 0) ? a0 : ((lane == 1 && tA == 2) ? a1 : 0);
                    }
                }
                if (lenB <= 64) {
                    if (tB == 0) { if (lane < lenB) eB = pool_[offB + lane]; }
                    else {
                        u32 b0 = (u32)RB & EMASK, b1 = (u32)(RB >> 26) & EMASK;
                        eB = (lane == 0) ? b0 : ((lane == 1 && tB == 2) ? b1 : 0);
                    }
                }
                u32 eS, eL; int lenS, lenL, offS, offL, capL, tL;
                if (lenA <= lenB) { eS=eA; lenS=lenA; offS=offA; eL=eB; lenL=lenB; offL=offB; capL=capB; tL=tB; }
                else              { eS=eB; lenS=lenB; offS=offB; eL=eA; lenL=lenA; offL=offA; capL=capA; tL=tA; }
                int dOff, dLen, dCap;
                int same = 0;
                u64 newR;

                if (lenS + lenL <= 64) {
                    dLen = lenL;
                    for (int t = 0; t < lenS; ++t) {
                        u32 xs = (u32)rdl((int)eS, t);
                        bool match = (lane < lenL) && ((eL >> 16) == (xs >> 16));
                        u64 mb = __ballot(match);
                        if (mb) {
                            int ml = __ffsll(mb) - 1;
                            same += (int)(xs & 0xFFFF) * ((int)rdl((int)eL, ml) & 0xFFFF);
                            if (match) eL += (xs & 0xFFFF);
                        } else {
                            if (lane == dLen) eL = xs;
                            dLen++;
                        }
                    }
                    if (dLen <= 2) {
                        u32 m0 = (u32)rdl((int)eL, 0) & EMASK;
                        u32 m1 = (dLen > 1) ? ((u32)rdl((int)eL, 1) & EMASK) : 0u;
                        newR = ((u64)(u32)dLen << 62) | ((u64)m1 << 26) | m0;
                    } else {
                        if (tL == 0 && dLen <= capL) { dOff = offL; dCap = capL; }
                        else { dOff = (int)bump; dCap = (dLen + 3) & ~3; bump += (u32)dCap; }
                        if (lane < dLen) pool_[dOff + lane] = eL;
                        newR = packRoot(sLa + sLb, dOff, dLen, dCap);
                    }
                } else {
                    dOff = (int)bump;
                    dCap = (lenL + lenS + 4) & ~3; bump += (u32)dCap;
                    if (lenS <= 64) {
                        if (lane < lenS) H_[eS >> 16] = (short)(eS & 0xFFFF);
                    } else {
                        for (int j = lane; j < lenS; j += 64) {
                            u32 es = pool_[offS + j];
                            H_[es >> 16] = (short)(es & 0xFFFF);
                        }
                    }
                    __builtin_amdgcn_wave_barrier();
                    int sp = 0;
                    for (int j = lane; j < lenL; j += 64) {
                        u32 el = pool_[offL + j];
                        int h = (int)H_[el >> 16];
                        sp += h * (int)(el & 0xFFFF);
                        pool_[dOff + j] = el + (u32)h;
                        if (h) H_[el >> 16] = 0;
                    }
                    same = wredi(sp);
                    __builtin_amdgcn_wave_barrier();
                    int baseU = 0;
                    if (lenS <= 64) {
                        bool un = (lane < lenS) && (H_[eS >> 16] != 0);
                        u64 ub = __ballot(un);
                        if (un) {
                            int pos = __popcll(ub & ltm);
                            pool_[dOff + lenL + pos] = eS;
                            H_[eS >> 16] = 0;
                        }
                        baseU = (int)__popcll(ub);
                    } else {
                        for (int j0 = 0; j0 < lenS; j0 += 64) {
                            int j = j0 + lane;
                            bool un = false; u32 es = 0;
                            if (j < lenS) { es = pool_[offS + j]; un = (H_[es >> 16] != 0); }
                            u64 ub = __ballot(un);
                            if (un) {
                                int pos = __popcll(ub & ltm);
                                pool_[dOff + lenL + baseU + pos] = es;
                                H_[es >> 16] = 0;
                            }
                            baseU += (int)__popcll(ub);
                        }
                    }
                    dLen = lenL + baseU;
                    newR = packRoot(sLa + sLb, dOff, dLen, dCap);
                }
                if (lane == 0) {
                    Qw_[qi] = (float)(ph ? same : (sLa * sLb - same));
                    Q_[qi]  = (unsigned short)e;
                    root_[A] = newR;
                    root_[B] = 0;
                }
                __builtin_amdgcn_wave_barrier();
            }

            if (av) {
                for (;;) {
                    int va = (int)(unsigned short)par_[ra];
                    int vb = (int)(unsigned short)par_[rb];
                    int pa = va & 0x3FF, pb = vb & 0x3FF;
                    bool fa = (pa != ra), fb = (pb != rb);
                    if (!fa && !fb) { laA = va >> 15; laB = vb >> 15; break; }
                    int ga = (int)(unsigned short)par_[pa];
                    int gb = (int)(unsigned short)par_[pb];
                    if (fa) { par_[ra] = (short)ga; ra = ga & 0x3FF; }
                    if (fb) { par_[rb] = (short)gb; rb = gb & 0x3FF; }
                }
                alive = !go && (ra != rb);
            }
        }
        curE = nextE;
        __builtin_amdgcn_wave_barrier();
    }

    // ---- epilogue ----
    float s_loc = 0.0f;
    for (int q = lane; q < qn; q += 64) s_loc += Qw_[q];
    const float sn = wredf(s_loc);

    const float scale = ph ? lrp_p[0] : lr_p[0];
    float acc = 0.0f;
    for (int q = lane; q < qn; q += 64) {
        float wv2 = Qw_[q];
        if (wv2 == 0.0f) continue;
        if (sn > 0.0f) wv2 /= sn;
        int me = (int)Q_[q];
        int g = gtcL[me];
        bool zero = ph ? (g < 20) : (g >= 10);
        if (zero) continue;
        int a2, b2; edgeAB(me, a2, b2);
        float pa = predL[a2], pb = predL[b2];
        float fa2, fb2;
        if (ph == 0) { fa2 = pa * pa; fb2 = pb * pb; }
        else { float qa = 20.0f - pa, qb = 20.0f - pb; fa2 = qa * qa; fb2 = qb * qb; }
        acc += scale * wv2 * (fa2 + fb2);
    }
    acc = wredf(acc);
    if (lane == 0) atomicAdd(out, acc);
}

__global__ void zero_out_kernel(float* o)
{
    if (threadIdx.x == 0 && blockIdx.x == 0) o[0] = 0.0f;
}

extern "C" void kernel_launch(void* const* d_in, const int* in_sizes, int n_in,
                              void* d_out, int out_size, void* d_ws, size_t ws_size,
                              hipStream_t stream)
{
    const float* pred   = (const float*)d_in[0];
    const float* target = (const float*)d_in[1];
    const float* lr     = (const float*)d_in[2];
    const float* lrp    = (const float*)d_in[3];
    float* out = (float*)d_out;

    zero_out_kernel<<<1, 64, 0, stream>>>(out);
    malis_kernel<<<256, 64, 0, stream>>>(pred, target, lr, lrp, out);
}

// Round 9
// 321.167 us; speedup vs baseline: 1.0833x; 1.0833x over previous
//
#include <hip/hip_runtime.h>
#include <cstdint>

#define NPIX  1024
#define NH    992
#define NEDGE 1984
#define NSORT 2048
#define NGRP  31
#define HFS   4300
#define POOLN (NPIX + 2*HFS)   // 9624 u32 entries

typedef unsigned long long u64;
typedef unsigned int u32;

// ---- root_ encoding ----
// 0 == dead/unlabeled.
// type = bits[62,64): 0 = pool-backed, 1 = inline x1, 2 = inline x2.
// pool-backed: sL[0,11) | off[11,25) | len[25,36) | cap[36,47)
// inline: entry k at bits[26k, 26k+26), entry = lab<<16 | cnt
static __device__ __forceinline__ u64 packRoot(int sL,int off,int len,int cap){
    return (u64)(u32)(sL & 0x7FF) | ((u64)(u32)(off & 0x3FFF) << 11) |
           ((u64)(u32)(len & 0x7FF) << 25) | ((u64)(u32)(cap & 0x7FF) << 36);
}
#define R_SL(R)  ((int)((R) & 0x7FF))
#define R_OFF(R) ((int)(((R)>>11) & 0x3FFF))
#define R_LEN(R) ((int)(((R)>>25) & 0x7FF))
#define R_CAP(R) ((int)(((R)>>36) & 0x7FF))
#define EMASK 0x3FFFFFFu

static __device__ __forceinline__ int rdl(int v, int l){ return __builtin_amdgcn_readlane(v, l); }

static __device__ __forceinline__ u64 sxor64(u64 v, int m){
    u32 lo = (u32)__shfl_xor((int)(v & 0xFFFFFFFFull), m, 64);
    u32 hi = (u32)__shfl_xor((int)(v >> 32), m, 64);
    return ((u64)hi << 32) | lo;
}

// edge id -> endpoints (reference order: 992 horizontal then 992 vertical)
static __device__ __forceinline__ void edgeAB(int e, int &a, int &b){
    if (e < NH) { int r = (int)((unsigned)e / 31u); a = e + r; b = a + 1; }
    else        { a = e - NH; b = a + 32; }
}

static __device__ __forceinline__ int winBase(int wslot){
    int bb = wslot >> 6;
    int win = wslot & 63;
    int wy = win >> 3, wx = win & 7;
    return bb * 65536 + (wy * 32) * 256 + wx * 32;
}

// in-register compare-exchange: x at lower global index
#define CE(x, y, up) { u64 _a=(x), _b=(y); bool _lt=(_a<_b); \
    u64 _mn=_lt?_a:_b, _mx=_lt?_b:_a; (x)=(up)?_mn:_mx; (y)=(up)?_mx:_mn; }
// cross-lane compare-exchange via shfl_xor
#define CEX(x, xm, keepmin) { u64 _p=sxor64((x),(xm)); bool _lt=((x)<_p); \
    u64 _mn=_lt?(x):_p, _mx=_lt?_p:(x); (x)=(keepmin)?_mn:_mx; }

static __device__ __forceinline__ int wredi(int v){
    #pragma unroll
    for (int o = 32; o > 0; o >>= 1) v += __shfl_xor(v, o, 64);
    return v;
}
static __device__ __forceinline__ float wredf(float v){
    #pragma unroll
    for (int o = 32; o > 0; o >>= 1) v += __shfl_xor(v, o, 64);
    return v;
}

// ===== fully fused: one block per (window, phase); 256 blocks x 64 threads =====
__global__ __launch_bounds__(64) void malis_kernel(
    const float* __restrict__ pred,
    const float* __restrict__ target,
    const float* __restrict__ lr_p,
    const float* __restrict__ lrp_p,
    float* __restrict__ out)
{
    const int lane = threadIdx.x;
    const int bid  = blockIdx.x;          // 0..255
    const int ph   = bid & 1;
    const int wslot= bid >> 1;
    const int base = winBase(wslot);
    const u64 ltm = (1ull << lane) - 1;

    // ---- LDS (~87 KB; 1 block/CU) ----
    __shared__ __align__(16) u32 Ks_[NSORT];   // 8192 sorted edge ids (this phase)
    __shared__ u64   root_[NPIX];              // 8192
    __shared__ u32   pool_[POOLN];             // 38496
    __shared__ unsigned short Q_[NPIX];        // 2048
    __shared__ float Qw_[NPIX];                // 4096
    __shared__ u32   claim_[NPIX];             // 4096  weighted-merge claims only
    __shared__ short par_[NPIX];               // 2048  parent[9:0] | labeled<<15
    __shared__ short H_[NPIX + 1];             // 2050
    __shared__ float predL[NPIX];              // 4096
    __shared__ float costs[NEDGE];             // 7936
    __shared__ short seg[NPIX];                // 2048
    __shared__ unsigned char tgtL[NPIX];       // 1024
    __shared__ unsigned char gtcL[NEDGE];      // 1984
    __shared__ u32   rowmaskL[32];             // 128
    __shared__ u32   fgL[32];                  // 128
    __shared__ unsigned short baseL[33];       // 66

    // early scratch overlaid on pool_ (dead until drain merges write it)
    u32* runPar = (u32*)pool_;                                  // 512 u32
    unsigned short* labIdRun = (unsigned short*)(runPar + 512); // 512 u16

    // ---- load window; (target==0) row bitmasks via ballot ----
    for (int j = 0; j < 16; ++j) {
        int i = lane + 64 * j;
        int r = (j << 1) + (lane >> 5), c = lane & 31;
        float pv = pred[base + r * 256 + c];
        float tv = target[base + r * 256 + c];
        predL[i] = pv;
        tgtL[i]  = (unsigned char)tv;
        u64 zb = __ballot(tv == 0.0f);
        if (lane == 0) {
            rowmaskL[2*j]     = (u32)zb;
            rowmaskL[2*j + 1] = (u32)(zb >> 32);
        }
    }
    for (int x = lane; x < 512; x += 64) runPar[x] = (u32)x;
    __builtin_amdgcn_wave_barrier();

    // ---- dilate 5x in lanes 0..31 (lane r holds row-r mask) ----
    if (lane < 32) {
        u32 m = rowmaskL[lane];
        #pragma unroll
        for (int it = 0; it < 5; ++it) {
            u32 um = __shfl(m, (lane == 0) ? 0 : lane - 1, 64);
            if (lane == 0) um = 0;
            u32 dm = __shfl(m, (lane == 31) ? 31 : lane + 1, 64);
            if (lane == 31) dm = 0;
            m = m | (m << 1) | (m >> 1) | um | dm;
        }
        u32 f = ~m;
        fgL[lane] = f;
        int ns = __popc(f & ~(f << 1));
        int x = ns;
        #pragma unroll
        for (int off = 1; off < 32; off <<= 1) {
            int y = __shfl(x, (lane >= off) ? lane - off : 0, 64);
            if (lane >= off) x += y;
        }
        baseL[lane] = (unsigned short)(x - ns);
        if (lane == 31) baseL[32] = (unsigned short)x;
    }
    __builtin_amdgcn_wave_barrier();
    const int nRuns = (int)baseL[32];

    // ---- CCL (8-conn) as union-find over row runs; single wave ----
    for (;;) {
        bool chg = false;
        for (int j = 0; j < 16; ++j) {
            int i = lane + 64 * j;
            int r = i >> 5, c = i & 31;
            if (r == 0) continue;
            u32 fr = fgL[r];
            if (!((fr >> c) & 1u)) continue;
            u32 fu = fgL[r - 1];
            u32 nb = fu & (u32)((7ull << c) >> 1);
            if (!nb) continue;
            u32 Sr = fr & ~(fr << 1);
            int a = (int)baseL[r] + __popc(Sr & ((2u << c) - 1u)) - 1;
            for (;;) { int p = (int)runPar[a]; if (p == a) break; a = p; }
            u32 Su = fu & ~(fu << 1);
            int bu = (int)baseL[r - 1];
            while (nb) {
                int cc = __ffs((int)nb) - 1; nb &= nb - 1;
                int b = bu + __popc(Su & ((2u << cc) - 1u)) - 1;
                for (;;) { int p = (int)runPar[b]; if (p == b) break; b = p; }
                if (a != b) {
                    int mnr = a < b ? a : b;
                    int mxr = a ^ b ^ mnr;
                    atomicMin(&runPar[mxr], (u32)mnr);
                    chg = true;
                    a = mnr;
                }
            }
        }
        if (!__ballot(chg)) break;
        for (int x = lane; x < nRuns; x += 64) {
            u32 p = runPar[x];
            runPar[x] = runPar[p];
        }
        __builtin_amdgcn_wave_barrier();
    }

    // compact label ids over run roots via ballot prefix (deterministic)
    {
        int kacc = 0;
        for (int x0 = 0; x0 < nRuns; x0 += 64) {
            int x = x0 + lane;
            bool isr = (x < nRuns) && ((int)runPar[x] == x);
            u64 bm = __ballot(isr);
            if (isr) labIdRun[x] = (unsigned short)(kacc + (int)__popcll(bm & ltm));
            kacc += (int)__popcll(bm);
        }
    }
    __builtin_amdgcn_wave_barrier();

    // seg per pixel
    for (int j = 0; j < 16; ++j) {
        int i = lane + 64 * j;
        int r = i >> 5, c = i & 31;
        u32 fr = fgL[r];
        short s = 0;
        if ((fr >> c) & 1u) {
            u32 Sr = fr & ~(fr << 1);
            int x = (int)baseL[r] + __popc(Sr & ((2u << c) - 1u)) - 1;
            for (;;) { int p = (int)runPar[x]; if (p == x) break; x = p; }
            s = (short)((int)labIdRun[x] + 1);
        }
        seg[i] = s;
    }

    // ---- edge costs ----
    for (int e = lane; e < NEDGE; e += 64) {
        int a, b2; edgeAB(e, a, b2);
        costs[e] = predL[a] + predL[b2];
        gtcL[e]  = (unsigned char)(tgtL[a] + tgtL[b2]);
    }
    __builtin_amdgcn_wave_barrier();

    // ---- register-resident bitonic sort of 2048 u64 keys (this phase) ----
    u64 sk[32];
    #pragma unroll
    for (int r = 0; r < 32; ++r) {
        int e = lane * 32 + r;
        u64 kv = ~0ULL;
        if (e < NEDGE) {
            float cv = costs[e];
            int g = gtcL[e];
            if (ph == 0) { if (g > 20) cv = 20.0f; }
            else         { if (g < 10) cv = 0.0f; }
            kv = (((u64)(~__float_as_uint(cv))) << 32) | (u32)e;
        }
        sk[r] = kv;
    }
    #pragma unroll
    for (int kk2 = 2; kk2 <= 32; kk2 <<= 1) {
        #pragma unroll
        for (int j = kk2 >> 1; j > 0; j >>= 1) {
            #pragma unroll
            for (int r = 0; r < 32; ++r) {
                if ((r & j) == 0) {
                    bool up = (kk2 == 32) ? ((lane & 1) == 0) : ((r & kk2) == 0);
                    CE(sk[r], sk[r | j], up);
                }
            }
        }
    }
    #pragma unroll
    for (int kk2 = 64; kk2 <= 2048; kk2 <<= 1) {
        const bool up = ((lane & (kk2 >> 5)) == 0);
        #pragma unroll
        for (int j = kk2 >> 1; j >= 32; j >>= 1) {
            const int xm = j >> 5;
            const bool keepmin = (((lane & xm) == 0) == up);
            #pragma unroll
            for (int r = 0; r < 32; ++r) { CEX(sk[r], xm, keepmin); }
        }
        #pragma unroll
        for (int j = 16; j > 0; j >>= 1) {
            #pragma unroll
            for (int r = 0; r < 32; ++r) {
                if ((r & j) == 0) { CE(sk[r], sk[r | j], up); }
            }
        }
    }
    #pragma unroll
    for (int r = 0; r < 32; r += 4) {
        uint4 v4;
        v4.x = (u32)sk[r]; v4.y = (u32)sk[r+1]; v4.z = (u32)sk[r+2]; v4.w = (u32)sk[r+3];
        *(uint4*)&Ks_[lane * 32 + r] = v4;
    }

    // ---- union-find init; labeled pixel i starts as INLINE singleton ----
    for (int i = lane; i < NPIX; i += 64) {
        short s2 = seg[i];
        par_[i] = (short)(i | (s2 ? 0x8000 : 0));
        root_[i] = s2 ? ((1ull << 62) | ((u32)(unsigned short)s2 << 16) | 1u) : 0ull;
        H_[i] = 0;
        claim_[i] = ~0u;
    }
    if (lane == 0) H_[NPIX] = 0;
    __builtin_amdgcn_wave_barrier();

    // ---- pool allocator + gc (rare path) ----
    u32 bump = NPIX;
    u32 halfEnd = NPIX + HFS;
    int curHalf = 0;

    auto do_gc = [&]() {
        u32 tgt = (curHalf == 0) ? (u32)(NPIX + HFS) : (u32)NPIX;
        u32 nb = tgt;
        for (int c = 0; c < 16; ++c) {
            int i0 = c * 64 + lane;
            u64 Ri = root_[i0];
            bool live = (Ri != 0) && ((Ri >> 62) == 0);
            u64 rbm = __ballot(live);
            while (rbm) {
                int j = __ffsll(rbm) - 1; rbm &= rbm - 1;
                int r = c * 64 + j;
                u64 R = root_[r];
                int len = R_LEN(R);
                int off = R_OFF(R);
                for (int t = lane; t < len; t += 64) {
                    u32 v2 = pool_[off + t];
                    pool_[nb + t] = v2;
                }
                __builtin_amdgcn_wave_barrier();
                if (lane == 0) root_[r] = packRoot(R_SL(R), (int)nb, len, len);
                nb += (u32)len;
            }
        }
        bump = nb;
        halfEnd = tgt + HFS;
        curHalf ^= 1;
    };

    // ---- Kruskal drain with fused accounting; claims for WEIGHTED merges only ----
    // Invariant: plumbing/mixed losers are UNLABELED roots; weighted losers are
    // LABELED roots => disjoint par_ addresses. Plumbing/mixed therefore write
    // par_[loser]=winner directly (HW picks one writer per address; losers retry
    // via refresh). Acyclic: unlabeled parents only become smaller-unlabeled or
    // labeled; labeled addresses are written only by claim-protected weighted
    // merges (pairwise-disjoint {winner,loser} per round). Plumbing/mixed never
    // change labeled-set contents => weights stay exact; weighted order enforced
    // by versioned lane-tag claims on BOTH roots. Solo rounds skip claims.
    int qn = 0;
    u32 rnd = 1;
    int curE = (int)Ks_[lane];
    for (int g2 = 0; g2 < NGRP; ++g2) {
        int nextE = (g2 + 1 < NGRP) ? (int)Ks_[(g2 + 1) * 64 + lane] : 0;
        const int myE = curE;
        int ea, eb2; edgeAB(myE, ea, eb2);
        int ra = ea, rb = eb2;
        int laA, laB;
        for (;;) {
            int va = (int)(unsigned short)par_[ra];
            int vb = (int)(unsigned short)par_[rb];
            int pa = va & 0x3FF, pb = vb & 0x3FF;
            bool fa = (pa != ra), fb = (pb != rb);
            if (!fa && !fb) { laA = va >> 15; laB = vb >> 15; break; }
            int ga = (int)(unsigned short)par_[pa];
            int gb = (int)(unsigned short)par_[pb];
            if (fa) { par_[ra] = (short)ga; ra = ga & 0x3FF; }
            if (fb) { par_[rb] = (short)gb; rb = gb & 0x3FF; }
        }
        bool alive = (ra != rb);

        for (;;) {
            u64 aliveB = __ballot(alive);
            if (!aliveB) break;
            const bool av = alive;
            const bool solo = (aliveB & (aliveB - 1)) == 0;
            const u32 tag = ((0x03FFFFFFu - rnd) << 6) | (u32)lane;
            ++rnd;
            int mn = ra < rb ? ra : rb;
            int mx = ra ^ rb ^ mn;
            int winner = (laA == laB) ? mn : (laA ? ra : rb);
            int loser  = (laA == laB) ? mx : (laA ? rb : ra);
            bool wgt = (laA & laB) != 0;

            // speculative round-start root reads (sel lane holds both exclusively;
            // lockstep: all reads precede all writes this round)
            u64 RW = 0, RL = 0;
            if (av && wgt) { RW = root_[mn]; RL = root_[mx]; }

            u64 wgtB = __ballot(av && wgt);
            bool goW = false;
            if (wgtB) {
                if (solo) {
                    goW = av && wgt;
                } else {
                    if (av && wgt) { atomicMin(&claim_[loser], tag);
                                     atomicMin(&claim_[winner], tag); }
                    if (av && wgt) {
                        u32 cl = claim_[loser];
                        u32 cw = claim_[winner];
                        goW = (cl == tag) && (cw == tag);
                    }
                }
            }
            // plumbing/mixed: direct union (unlabeled loser addresses)
            if (av && !wgt) par_[loser] = (short)winner;
            if (goW)        par_[loser] = (short)winner;

            u64 wm = __ballot(goW);
            int qidx = qn + (int)__popcll(wm & ltm);
            qn += (int)__popcll(wm);

            // per-lane inline merge (winner = mn for weighted merges)
            bool needPool = false;
            if (goW) {
                int tW = (int)(RW >> 62), tL2 = (int)(RL >> 62);
                if (tW != 0 && tL2 != 0) {
                    u32 a0 = (u32)RW & EMASK, a1 = (u32)(RW >> 26) & EMASK;
                    u32 b0 = (u32)RL & EMASK, b1 = (u32)(RL >> 26) & EMASK;
                    u32 la0 = a0 >> 16, la1 = a1 >> 16;
                    u32 lb0 = b0 >> 16, lb1 = b1 >> 16;
                    int ca0 = (int)(a0 & 0xFFFF), ca1 = (int)(a1 & 0xFFFF);
                    int cb0 = (int)(b0 & 0xFFFF), cb1 = (int)(b1 & 0xFFFF);
                    int sLa = ca0 + ((tW == 2) ? ca1 : 0);
                    int sLb = cb0 + ((tL2 == 2) ? cb1 : 0);
                    int same = 0;
                    if (lb0 == la0) same += ca0 * cb0;
                    else if (tW == 2 && lb0 == la1) same += ca1 * cb0;
                    if (tL2 == 2) {
                        if (lb1 == la0) same += ca0 * cb1;
                        else if (tW == 2 && lb1 == la1) same += ca1 * cb1;
                    }
                    u32 r0 = a0, r1 = (tW == 2) ? a1 : 0;
                    int n = tW; bool ovf = false;
                    if (lb0 == la0) r0 += (u32)cb0;
                    else if (tW == 2 && lb0 == la1) r1 += (u32)cb0;
                    else { if (n == 1) { r1 = b0; n = 2; } else ovf = true; }
                    if (tL2 == 2) {
                        if (lb1 == la0) r0 += (u32)cb1;
                        else if (tW == 2 && lb1 == la1) r1 += (u32)cb1;
                        else { if (n == 1) { r1 = b1; n = 2; } else ovf = true; }
                    }
                    if (!ovf) {
                        root_[mn] = ((u64)(u32)n << 62) | ((u64)r1 << 26) | r0;
                        root_[mx] = 0;
                        Qw_[qidx] = (float)(ph ? same : (sLa * sLb - same));
                        Q_[qidx]  = (unsigned short)myE;
                    } else needPool = true;
                } else needPool = true;
            }

            // wave-wide pool merges (rare)
            u64 pm = __ballot(needPool);
            while (pm) {
                int f = __ffsll(pm) - 1; pm &= pm - 1;
                int A  = rdl(mn, f),  B  = rdl(mx, f);
                int e  = rdl(myE, f), qi = rdl(qidx, f);
                u64 RA = root_[A], RB = root_[B];
                int tA = (int)(RA >> 62), tB = (int)(RB >> 62);
                int lenA = tA ? tA : R_LEN(RA);
                int lenB = tB ? tB : R_LEN(RB);
                if (bump + (u32)(lenA + lenB + 8) > halfEnd) {
                    do_gc();
                    RA = root_[A]; RB = root_[B];
                    tA = (int)(RA >> 62); tB = (int)(RB >> 62);
                    lenA = tA ? tA : R_LEN(RA);
                    lenB = tB ? tB : R_LEN(RB);
                }
                int sLa, sLb;
                int offA = 0, capA = 0, offB = 0, capB = 0;
                if (tA == 0) { sLa = R_SL(RA); offA = R_OFF(RA); capA = R_CAP(RA); }
                else {
                    u32 a0 = (u32)RA & EMASK, a1 = (u32)(RA >> 26) & EMASK;
                    sLa = (int)(a0 & 0xFFFF) + ((tA == 2) ? (int)(a1 & 0xFFFF) : 0);
                }
                if (tB == 0) { sLb = R_SL(RB); offB = R_OFF(RB); capB = R_CAP(RB); }
                else {
                    u32 b0 = (u32)RB & EMASK, b1 = (u32)(RB >> 26) & EMASK;
                    sLb = (int)(b0 & 0xFFFF) + ((tB == 2) ? (int)(b1 & 0xFFFF) : 0);
                }
                u32 eA = 0, eB = 0;
                if (lenA <= 64) {
                    if (tA == 0) { if (lane < lenA) eA = pool_[offA + lane]; }
                    else {
                        u32 a0 = (u32)RA & EMASK, a1 = (u32)(RA >> 26) & EMASK;
                        eA = (lane == 0) ? a0 : ((lane == 1 && tA == 2) ? a1 : 0);
                    }
                }
                if (lenB <= 64) {
                    if (tB == 0) { if (lane < lenB) eB = pool_[offB + lane]; }
                    else {
                        u32 b0 = (u32)RB & EMASK, b1 = (u32)(RB >> 26) & EMASK;
                        eB = (lane == 0) ? b0 : ((lane == 1 && tB == 2) ? b1 : 0);
                    }
                }
                u32 eS, eL; int lenS, lenL, offS, offL, capL, tL;
                if (lenA <= lenB) { eS=eA; lenS=lenA; offS=offA; eL=eB; lenL=lenB; offL=offB; capL=capB; tL=tB; }
                else              { eS=eB; lenS=lenB; offS=offB; eL=eA; lenL=lenA; offL=offA; capL=capA; tL=tA; }
                int dOff, dLen, dCap;
                int same = 0;
                u64 newR;

                if (lenS + lenL <= 64) {
                    dLen = lenL;
                    for (int t = 0; t < lenS; ++t) {
                        u32 xs = (u32)rdl((int)eS, t);
                        bool match = (lane < lenL) && ((eL >> 16) == (xs >> 16));
                        u64 mb = __ballot(match);
                        if (mb) {
                            int ml = __ffsll(mb) - 1;
                            same += (int)(xs & 0xFFFF) * ((int)rdl((int)eL, ml) & 0xFFFF);
                            if (match) eL += (xs & 0xFFFF);
                        } else {
                            if (lane == dLen) eL = xs;
                            dLen++;
                        }
                    }
                    if (dLen <= 2) {
                        u32 m0 = (u32)rdl((int)eL, 0) & EMASK;
                        u32 m1 = (dLen > 1) ? ((u32)rdl((int)eL, 1) & EMASK) : 0u;
                        newR = ((u64)(u32)dLen << 62) | ((u64)m1 << 26) | m0;
                    } else {
                        if (tL == 0 && dLen <= capL) { dOff = offL; dCap = capL; }
                        else { dOff = (int)bump; dCap = (dLen + 3) & ~3; bump += (u32)dCap; }
                        if (lane < dLen) pool_[dOff + lane] = eL;
                        newR = packRoot(sLa + sLb, dOff, dLen, dCap);
                    }
                } else {
                    dOff = (int)bump;
                    dCap = (lenL + lenS + 4) & ~3; bump += (u32)dCap;
                    if (lenS <= 64) {
                        if (lane < lenS) H_[eS >> 16] = (short)(eS & 0xFFFF);
                    } else {
                        for (int j = lane; j < lenS; j += 64) {
                            u32 es = pool_[offS + j];
                            H_[es >> 16] = (short)(es & 0xFFFF);
                        }
                    }
                    __builtin_amdgcn_wave_barrier();
                    int sp = 0;
                    for (int j = lane; j < lenL; j += 64) {
                        u32 el = pool_[offL + j];
                        int h = (int)H_[el >> 16];
                        sp += h * (int)(el & 0xFFFF);
                        pool_[dOff + j] = el + (u32)h;
                        if (h) H_[el >> 16] = 0;
                    }
                    same = wredi(sp);
                    __builtin_amdgcn_wave_barrier();
                    int baseU = 0;
                    if (lenS <= 64) {
                        bool un = (lane < lenS) && (H_[eS >> 16] != 0);
                        u64 ub = __ballot(un);
                        if (un) {
                            int pos = __popcll(ub & ltm);
                            pool_[dOff + lenL + pos] = eS;
                            H_[eS >> 16] = 0;
                        }
                        baseU = (int)__popcll(ub);
                    } else {
                        for (int j0 = 0; j0 < lenS; j0 += 64) {
                            int j = j0 + lane;
                            bool un = false; u32 es = 0;
                            if (j < lenS) { es = pool_[offS + j]; un = (H_[es >> 16] != 0); }
                            u64 ub = __ballot(un);
                            if (un) {
                                int pos = __popcll(ub & ltm);
                                pool_[dOff + lenL + baseU + pos] = es;
                                H_[es >> 16] = 0;
                            }
                            baseU += (int)__popcll(ub);
                        }
                    }
                    dLen = lenL + baseU;
                    newR = packRoot(sLa + sLb, dOff, dLen, dCap);
                }
                if (lane == 0) {
                    Qw_[qi] = (float)(ph ? same : (sLa * sLb - same));
                    Q_[qi]  = (unsigned short)e;
                    root_[A] = newR;
                    root_[B] = 0;
                }
                __builtin_amdgcn_wave_barrier();
            }

            if (av) {
                for (;;) {
                    int va = (int)(unsigned short)par_[ra];
                    int vb = (int)(unsigned short)par_[rb];
                    int pa = va & 0x3FF, pb = vb & 0x3FF;
                    bool fa = (pa != ra), fb = (pb != rb);
                    if (!fa && !fb) { laA = va >> 15; laB = vb >> 15; break; }
                    int ga = (int)(unsigned short)par_[pa];
                    int gb = (int)(unsigned short)par_[pb];
                    if (fa) { par_[ra] = (short)ga; ra = ga & 0x3FF; }
                    if (fb) { par_[rb] = (short)gb; rb = gb & 0x3FF; }
                }
                alive = (ra != rb);
            }
        }
        curE = nextE;
        __builtin_amdgcn_wave_barrier();
    }

    // ---- epilogue ----
    float s_loc = 0.0f;
    for (int q = lane; q < qn; q += 64) s_loc += Qw_[q];
    const float sn = wredf(s_loc);

    const float scale = ph ? lrp_p[0] : lr_p[0];
    float acc = 0.0f;
    for (int q = lane; q < qn; q += 64) {
        float wv2 = Qw_[q];
        if (wv2 == 0.0f) continue;
        if (sn > 0.0f) wv2 /= sn;
        int me = (int)Q_[q];
        int g = gtcL[me];
        bool zero = ph ? (g < 20) : (g >= 10);
        if (zero) continue;
        int a2, b2; edgeAB(me, a2, b2);
        float pa = predL[a2], pb = predL[b2];
        float fa2, fb2;
        if (ph == 0) { fa2 = pa * pa; fb2 = pb * pb; }
        else { float qa = 20.0f - pa, qb = 20.0f - pb; fa2 = qa * qa; fb2 = qb * qb; }
        acc += scale * wv2 * (fa2 + fb2);
    }
    acc = wredf(acc);
    if (lane == 0) atomicAdd(out, acc);
}

__global__ void zero_out_kernel(float* o)
{
    if (threadIdx.x == 0 && blockIdx.x == 0) o[0] = 0.0f;
}

extern "C" void kernel_launch(void* const* d_in, const int* in_sizes, int n_in,
                              void* d_out, int out_size, void* d_ws, size_t ws_size,
                              hipStream_t stream)
{
    const float* pred   = (const float*)d_in[0];
    const float* target = (const float*)d_in[1];
    const float* lr     = (const float*)d_in[2];
    const float* lrp    = (const float*)d_in[3];
    float* out = (float*)d_out;

    zero_out_kernel<<<1, 64, 0, stream>>>(out);
    malis_kernel<<<256, 64, 0, stream>>>(pred, target, lr, lrp, out);
}